// Round 7
// baseline (810.014 us; speedup 1.0000x reference)
//
#include <hip/hip_runtime.h>

#define N_NODES 100000
#define N_EDGES 1600000
#define HID 128
#define LAT 64
#define N_LAYERS 3
#define N_GRAPHS 1000
#define NB_SCAN ((N_NODES + 255) / 256)   // 391
#define BKT_SHIFT 6                        // 64 nodes per bucket
#define N_BKT ((N_NODES + 63) / 64)        // 1563

typedef short bf16x8 __attribute__((ext_vector_type(8)));
typedef float f32x4 __attribute__((ext_vector_type(4)));

__device__ __forceinline__ float bf2f(unsigned short h) {
    union { unsigned int u; float f; } c;
    c.u = ((unsigned int)h) << 16;
    return c.f;
}
__device__ __forceinline__ unsigned short f2bf(float f) {
    union { float f; unsigned int u; } c;
    c.f = f;
    unsigned int u = c.u;
    return (unsigned short)((u + 0x7fffu + ((u >> 16) & 1u)) >> 16);
}
__device__ __forceinline__ unsigned int pack2(float a, float b) {
    return (unsigned int)f2bf(a) | ((unsigned int)f2bf(b) << 16);
}
__device__ __forceinline__ void addrow(float* acc, uint4 w) {
    acc[0] += bf2f((unsigned short)w.x); acc[1] += bf2f((unsigned short)(w.x >> 16));
    acc[2] += bf2f((unsigned short)w.y); acc[3] += bf2f((unsigned short)(w.y >> 16));
    acc[4] += bf2f((unsigned short)w.z); acc[5] += bf2f((unsigned short)(w.z >> 16));
    acc[6] += bf2f((unsigned short)w.w); acc[7] += bf2f((unsigned short)(w.w >> 16));
}

// ---------------- convert x fp32 -> bf16 ----------------
__global__ __launch_bounds__(256) void cvt_x_kernel(const float* __restrict__ x,
                                                    unsigned short* __restrict__ xb, int n4) {
    int i = blockIdx.x * 256 + threadIdx.x;
    if (i >= n4) return;
    float4 v = ((const float4*)x)[i];
    ((uint2*)xb)[i] = make_uint2(pack2(v.x, v.y), pack2(v.z, v.w));
}

// ---------------- W [k][n] fp32 -> Wt [n][k] bf16, 6 matrices ----------------
__global__ __launch_bounds__(256) void wt_kernel(const float* __restrict__ W1,
                                                 const float* __restrict__ W2,
                                                 unsigned short* __restrict__ Wt) {
    int m = blockIdx.x;  // 0..5 : layer*2 + phase
    const float* W = ((m & 1) ? W2 : W1) + (size_t)(m >> 1) * HID * HID;
    unsigned short* D = Wt + (size_t)m * HID * HID;
    for (int idx = threadIdx.x; idx < HID * HID; idx += 256) {
        int n = idx >> 7, k = idx & 127;
        D[n * HID + k] = f2bf(W[k * HID + n]);
    }
}

// ---------------- CSR build ----------------
__global__ __launch_bounds__(256) void count_kernel(const int* __restrict__ ei,
                                                    int* __restrict__ deg) {
    int e = blockIdx.x * 256 + threadIdx.x;
    if (e < N_EDGES) atomicAdd(&deg[ei[N_EDGES + e]], 1);
}

__global__ __launch_bounds__(256) void scanA_kernel(const int* __restrict__ deg,
                                                    int* __restrict__ bsum) {
    __shared__ int s[256];
    int t = threadIdx.x;
    int n = blockIdx.x * 256 + t;
    s[t] = (n < N_NODES) ? deg[n] : 0;
    __syncthreads();
    for (int d = 128; d > 0; d >>= 1) {
        if (t < d) s[t] += s[t + d];
        __syncthreads();
    }
    if (t == 0) bsum[blockIdx.x] = s[0];
}

__global__ __launch_bounds__(512) void scanB_kernel(const int* __restrict__ bsum,
                                                    int* __restrict__ boff) {
    __shared__ int s[512];
    int t = threadIdx.x;
    s[t] = (t < NB_SCAN) ? bsum[t] : 0;
    __syncthreads();
    for (int d = 1; d < 512; d <<= 1) {
        int v = (t >= d) ? s[t - d] : 0;
        __syncthreads();
        s[t] += v;
        __syncthreads();
    }
    if (t < NB_SCAN) boff[t] = (t == 0) ? 0 : s[t - 1];
}

__global__ __launch_bounds__(256) void scanC_kernel(const int* __restrict__ deg,
                                                    const int* __restrict__ boff,
                                                    int* __restrict__ offs,
                                                    int* __restrict__ cursor) {
    __shared__ int s[256];
    int t = threadIdx.x;
    int n = blockIdx.x * 256 + t;
    int v = (n < N_NODES) ? deg[n] : 0;
    s[t] = v;
    __syncthreads();
    for (int d = 1; d < 256; d <<= 1) {
        int u = (t >= d) ? s[t - d] : 0;
        __syncthreads();
        s[t] += u;
        __syncthreads();
    }
    if (n < N_NODES) {
        int bo = boff[blockIdx.x];
        int excl = bo + s[t] - v;
        offs[n] = excl;
        cursor[n] = excl;
        if (n == N_NODES - 1) offs[N_NODES] = bo + s[t];
    }
}

// ---------------- bucketed place ----------------
// bcur[b] = offs[min(b*64, N_NODES)] — append cursor for bucket b's ebuf region
__global__ __launch_bounds__(256) void binit_kernel(const int* __restrict__ offs,
                                                    int* __restrict__ bcur) {
    int b = blockIdx.x * 256 + threadIdx.x;
    if (b < N_BKT) {
        int n = b << BKT_SHIFT;
        if (n > N_NODES) n = N_NODES;
        bcur[b] = offs[n];
    }
}

// Phase A: scatter (src,dst) into per-bucket dense append regions of ebuf.
__global__ __launch_bounds__(256) void bucketA_kernel(const int* __restrict__ ei,
                                                      int* __restrict__ bcur,
                                                      uint2* __restrict__ ebuf) {
    int e = blockIdx.x * 256 + threadIdx.x;
    if (e < N_EDGES) {
        int s = ei[e];
        int d = ei[N_EDGES + e];
        int pos = atomicAdd(&bcur[d >> BKT_SHIFT], 1);
        ebuf[pos] = make_uint2((unsigned int)s, (unsigned int)d);
    }
}

// Phase B: one block per bucket; place src at cursor[dst] within the bucket's
// contiguous csr window (stays in this XCD's L2 — no write amplification).
__global__ __launch_bounds__(256) void bucketB_kernel(const int* __restrict__ offs,
                                                      const uint2* __restrict__ ebuf,
                                                      int* __restrict__ cursor,
                                                      int* __restrict__ csr) {
    int b = blockIdx.x;
    int n0 = b << BKT_SHIFT;
    int n1 = n0 + (1 << BKT_SHIFT);
    if (n1 > N_NODES) n1 = N_NODES;
    int r0 = offs[n0], r1 = offs[n1];
    for (int i = r0 + threadIdx.x; i < r1; i += 256) {
        uint2 ed = ebuf[i];
        int pos = atomicAdd(&cursor[ed.y], 1);
        csr[pos] = (int)ed.x;
    }
}

// ---------------- gather (bf16): agg[n] = h[n] + sum_{s in N(n)} h[s] ----------------
__global__ __launch_bounds__(256) void gather_kernel(const unsigned short* __restrict__ h,
                                                     const int* __restrict__ offs,
                                                     const int* __restrict__ csr,
                                                     unsigned short* __restrict__ agg) {
    int t = threadIdx.x;
    int node = blockIdx.x * 16 + (t >> 4);
    int q = t & 15;
    if (node >= N_NODES) return;
    int off0 = offs[node], off1 = offs[node + 1];
    float acc[8] = {0.f, 0.f, 0.f, 0.f, 0.f, 0.f, 0.f, 0.f};
    addrow(acc, *(const uint4*)(h + (size_t)node * HID + q * 8));
    int e = off0;
    for (; e + 8 <= off1; e += 8) {
        int s0 = csr[e], s1 = csr[e + 1], s2 = csr[e + 2], s3 = csr[e + 3];
        int s4 = csr[e + 4], s5 = csr[e + 5], s6 = csr[e + 6], s7 = csr[e + 7];
        uint4 w0 = *(const uint4*)(h + (size_t)s0 * HID + q * 8);
        uint4 w1 = *(const uint4*)(h + (size_t)s1 * HID + q * 8);
        uint4 w2 = *(const uint4*)(h + (size_t)s2 * HID + q * 8);
        uint4 w3 = *(const uint4*)(h + (size_t)s3 * HID + q * 8);
        uint4 w4 = *(const uint4*)(h + (size_t)s4 * HID + q * 8);
        uint4 w5 = *(const uint4*)(h + (size_t)s5 * HID + q * 8);
        uint4 w6 = *(const uint4*)(h + (size_t)s6 * HID + q * 8);
        uint4 w7 = *(const uint4*)(h + (size_t)s7 * HID + q * 8);
        addrow(acc, w0); addrow(acc, w1); addrow(acc, w2); addrow(acc, w3);
        addrow(acc, w4); addrow(acc, w5); addrow(acc, w6); addrow(acc, w7);
    }
    for (; e + 4 <= off1; e += 4) {
        int s0 = csr[e], s1 = csr[e + 1], s2 = csr[e + 2], s3 = csr[e + 3];
        uint4 w0 = *(const uint4*)(h + (size_t)s0 * HID + q * 8);
        uint4 w1 = *(const uint4*)(h + (size_t)s1 * HID + q * 8);
        uint4 w2 = *(const uint4*)(h + (size_t)s2 * HID + q * 8);
        uint4 w3 = *(const uint4*)(h + (size_t)s3 * HID + q * 8);
        addrow(acc, w0); addrow(acc, w1); addrow(acc, w2); addrow(acc, w3);
    }
    for (; e < off1; ++e) {
        addrow(acc, *(const uint4*)(h + (size_t)csr[e] * HID + q * 8));
    }
    uint4 o;
    o.x = pack2(acc[0], acc[1]);
    o.y = pack2(acc[2], acc[3]);
    o.z = pack2(acc[4], acc[5]);
    o.w = pack2(acc[6], acc[7]);
    *(uint4*)(agg + (size_t)node * HID + q * 8) = o;
}

// ---------------- MFMA MLP (round-5 proven) ----------------
__global__ __launch_bounds__(256) void mlp_kernel(const unsigned short* __restrict__ A,
                                                  const unsigned short* __restrict__ W1t,
                                                  const float* __restrict__ b1,
                                                  const unsigned short* __restrict__ W2t,
                                                  const float* __restrict__ b2,
                                                  unsigned short* __restrict__ out) {
    __shared__ unsigned short sA[64][136];  // row stride 272B = 17*16B
    __shared__ unsigned short sW[128][40];  // row stride 80B = 5*16B
    __shared__ float sb[128];
    const int t = threadIdx.x;
    const int w = t >> 6;
    const int l = t & 63;
    const int lm = l & 15;
    const int quad = l >> 4;
    const int row0 = blockIdx.x * 64;

    for (int idx = t; idx < 1024; idx += 256) {
        int r = idx >> 4, c = idx & 15;
        int grow = row0 + r;
        uint4 v = make_uint4(0u, 0u, 0u, 0u);
        if (grow < N_NODES) v = *(const uint4*)(A + (size_t)grow * HID + c * 8);
        *(uint4*)&sA[r][c * 8] = v;
    }

    const unsigned short* Wt[2] = {W1t, W2t};
    const float* bias[2] = {b1, b2};

    for (int p = 0; p < 2; ++p) {
        if (t < 128) sb[t] = bias[p][t];
        f32x4 acc[8];
#pragma unroll
        for (int nt = 0; nt < 8; ++nt) acc[nt] = (f32x4){0.f, 0.f, 0.f, 0.f};

        for (int kc = 0; kc < 4; ++kc) {
            __syncthreads();
            for (int idx = t; idx < 512; idx += 256) {
                int n = idx >> 2, kq = idx & 3;
                *(uint4*)&sW[n][kq * 8] =
                    *(const uint4*)(Wt[p] + (size_t)n * HID + kc * 32 + kq * 8);
            }
            __syncthreads();
            bf16x8 a = *(const bf16x8*)&sA[w * 16 + lm][kc * 32 + quad * 8];
#pragma unroll
            for (int nt = 0; nt < 8; ++nt) {
                bf16x8 b = *(const bf16x8*)&sW[nt * 16 + lm][quad * 8];
                acc[nt] = __builtin_amdgcn_mfma_f32_16x16x32_bf16(a, b, acc[nt], 0, 0, 0);
            }
        }
        __syncthreads();
#pragma unroll
        for (int nt = 0; nt < 8; ++nt) {
            float bv = sb[nt * 16 + lm];
#pragma unroll
            for (int r = 0; r < 4; ++r) {
                int m = w * 16 + quad * 4 + r;
                float val = fmaxf(acc[nt][r] + bv, 0.f);
                sA[m][nt * 16 + lm] = f2bf(val);
            }
        }
        __syncthreads();
    }
    for (int idx = t; idx < 1024; idx += 256) {
        int r = idx >> 4, c = idx & 15;
        int grow = row0 + r;
        if (grow < N_NODES)
            *(uint4*)(out + (size_t)grow * HID + c * 8) = *(const uint4*)&sA[r][c * 8];
    }
}

// ---------------- pool: g[batch[n]] += h[n] (batch sorted, bf16 in, fp32 out) ----------------
__global__ __launch_bounds__(128) void pool_kernel(const unsigned short* __restrict__ h,
                                                   const int* __restrict__ batch,
                                                   float* __restrict__ g) {
    const int CHUNK = 256;
    int c = threadIdx.x;
    int n0 = blockIdx.x * CHUNK;
    if (n0 >= N_NODES) return;
    int n1 = n0 + CHUNK;
    if (n1 > N_NODES) n1 = N_NODES;
    int cur = batch[n0];
    float acc = 0.f;
    for (int n = n0; n < n1; ++n) {
        int b = batch[n];
        if (b != cur) {
            atomicAdd(&g[(size_t)cur * HID + c], acc);
            acc = 0.f;
            cur = b;
        }
        acc += bf2f(h[(size_t)n * HID + c]);
    }
    atomicAdd(&g[(size_t)cur * HID + c], acc);
}

// ---------------- heads ----------------
__global__ __launch_bounds__(128) void head_kernel(const float* __restrict__ g,
                                                   const float* __restrict__ Wmu,
                                                   const float* __restrict__ bmu,
                                                   const float* __restrict__ Wlv,
                                                   const float* __restrict__ blv,
                                                   float* __restrict__ out) {
    __shared__ float sg[HID];
    int gi = blockIdx.x;
    sg[threadIdx.x] = g[(size_t)gi * HID + threadIdx.x];
    __syncthreads();
    int j = threadIdx.x & 63;
    bool is_lv = threadIdx.x >= 64;
    const float* W = is_lv ? Wlv : Wmu;
    float acc = is_lv ? blv[j] : bmu[j];
    for (int k = 0; k < HID; ++k) acc = fmaf(sg[k], W[k * LAT + j], acc);
    out[(is_lv ? (size_t)N_GRAPHS * LAT : 0) + (size_t)gi * LAT + j] = acc;
}

extern "C" void kernel_launch(void* const* d_in, const int* in_sizes, int n_in,
                              void* d_out, int out_size, void* d_ws, size_t ws_size,
                              hipStream_t stream) {
    const float* x     = (const float*)d_in[0];
    const int*   ei    = (const int*)d_in[1];
    const int*   batch = (const int*)d_in[2];
    const float* W1    = (const float*)d_in[3];
    const float* b1    = (const float*)d_in[4];
    const float* W2    = (const float*)d_in[5];
    const float* b2    = (const float*)d_in[6];
    const float* Wmu   = (const float*)d_in[7];
    const float* bmu   = (const float*)d_in[8];
    const float* Wlv   = (const float*)d_in[9];
    const float* blv   = (const float*)d_in[10];
    float* out = (float*)d_out;

    float* g = (float*)d_ws;
    unsigned short* xb   = (unsigned short*)(g + (size_t)N_GRAPHS * HID);
    unsigned short* agg  = xb + (size_t)N_NODES * HID;
    unsigned short* hbuf = agg + (size_t)N_NODES * HID;
    unsigned short* Wt   = hbuf + (size_t)N_NODES * HID;
    int* deg    = (int*)(Wt + (size_t)6 * HID * HID);
    int* offs   = deg + N_NODES;
    int* cursor = offs + N_NODES + 1;
    int* bsum   = cursor + N_NODES;
    int* boff   = bsum + NB_SCAN;
    int* bcur   = boff + NB_SCAN + 1;
    int* csr    = bcur + N_BKT;                     // 6.4 MB
    uint2* ebuf = (uint2*)(csr + N_EDGES);          // 12.8 MB

    // ---- CSR build (bucketed place) ----
    hipMemsetAsync(deg, 0, (size_t)N_NODES * sizeof(int), stream);
    count_kernel<<<(N_EDGES + 255) / 256, 256, 0, stream>>>(ei, deg);
    scanA_kernel<<<NB_SCAN, 256, 0, stream>>>(deg, bsum);
    scanB_kernel<<<1, 512, 0, stream>>>(bsum, boff);
    scanC_kernel<<<NB_SCAN, 256, 0, stream>>>(deg, boff, offs, cursor);
    binit_kernel<<<(N_BKT + 255) / 256, 256, 0, stream>>>(offs, bcur);
    bucketA_kernel<<<(N_EDGES + 255) / 256, 256, 0, stream>>>(ei, bcur, ebuf);
    bucketB_kernel<<<N_BKT, 256, 0, stream>>>(offs, ebuf, cursor, csr);

    // ---- prep bf16 ----
    cvt_x_kernel<<<(N_NODES * HID / 4 + 255) / 256, 256, 0, stream>>>(x, xb,
                                                                      N_NODES * HID / 4);
    wt_kernel<<<6, 256, 0, stream>>>(W1, W2, Wt);

    const unsigned short* hcur = xb;
    for (int i = 0; i < N_LAYERS; ++i) {
        gather_kernel<<<(N_NODES + 15) / 16, 256, 0, stream>>>(hcur, offs, csr, agg);
        mlp_kernel<<<(N_NODES + 63) / 64, 256, 0, stream>>>(
            agg, Wt + (size_t)(2 * i) * HID * HID, b1 + (size_t)i * HID,
            Wt + (size_t)(2 * i + 1) * HID * HID, b2 + (size_t)i * HID, hbuf);
        hcur = hbuf;
    }
    hipMemsetAsync(g, 0, (size_t)N_GRAPHS * HID * sizeof(float), stream);
    pool_kernel<<<(N_NODES + 255) / 256, 128, 0, stream>>>(hcur, batch, g);
    head_kernel<<<N_GRAPHS, 128, 0, stream>>>(g, Wmu, bmu, Wlv, blv, out);
}

// Round 8
// 639.277 us; speedup vs baseline: 1.2671x; 1.2671x over previous
//
#include <hip/hip_runtime.h>

#define N_NODES 100000
#define N_EDGES 1600000
#define HID 128
#define LAT 64
#define N_LAYERS 3
#define N_GRAPHS 1000
#define NB_SCAN ((N_NODES + 255) / 256)   // 391
#define N_PASS 8
#define PASS_W ((N_NODES + N_PASS - 1) / N_PASS)  // 12500

typedef short bf16x8 __attribute__((ext_vector_type(8)));
typedef float f32x4 __attribute__((ext_vector_type(4)));

__device__ __forceinline__ float bf2f(unsigned short h) {
    union { unsigned int u; float f; } c;
    c.u = ((unsigned int)h) << 16;
    return c.f;
}
__device__ __forceinline__ unsigned short f2bf(float f) {
    union { float f; unsigned int u; } c;
    c.f = f;
    unsigned int u = c.u;
    return (unsigned short)((u + 0x7fffu + ((u >> 16) & 1u)) >> 16);
}
__device__ __forceinline__ unsigned int pack2(float a, float b) {
    return (unsigned int)f2bf(a) | ((unsigned int)f2bf(b) << 16);
}
__device__ __forceinline__ void addrow(float* acc, uint4 w) {
    acc[0] += bf2f((unsigned short)w.x); acc[1] += bf2f((unsigned short)(w.x >> 16));
    acc[2] += bf2f((unsigned short)w.y); acc[3] += bf2f((unsigned short)(w.y >> 16));
    acc[4] += bf2f((unsigned short)w.z); acc[5] += bf2f((unsigned short)(w.z >> 16));
    acc[6] += bf2f((unsigned short)w.w); acc[7] += bf2f((unsigned short)(w.w >> 16));
}

// ---------------- convert x fp32 -> bf16 ----------------
__global__ __launch_bounds__(256) void cvt_x_kernel(const float* __restrict__ x,
                                                    unsigned short* __restrict__ xb, int n4) {
    int i = blockIdx.x * 256 + threadIdx.x;
    if (i >= n4) return;
    float4 v = ((const float4*)x)[i];
    ((uint2*)xb)[i] = make_uint2(pack2(v.x, v.y), pack2(v.z, v.w));
}

// ---------------- W [k][n] fp32 -> Wt [n][k] bf16, 6 matrices ----------------
__global__ __launch_bounds__(256) void wt_kernel(const float* __restrict__ W1,
                                                 const float* __restrict__ W2,
                                                 unsigned short* __restrict__ Wt) {
    int m = blockIdx.x;  // 0..5 : layer*2 + phase
    const float* W = ((m & 1) ? W2 : W1) + (size_t)(m >> 1) * HID * HID;
    unsigned short* D = Wt + (size_t)m * HID * HID;
    for (int idx = threadIdx.x; idx < HID * HID; idx += 256) {
        int n = idx >> 7, k = idx & 127;
        D[n * HID + k] = f2bf(W[k * HID + n]);
    }
}

// ---------------- CSR build ----------------
__global__ __launch_bounds__(256) void count_kernel(const int* __restrict__ ei,
                                                    int* __restrict__ deg) {
    int e = blockIdx.x * 256 + threadIdx.x;
    if (e < N_EDGES) atomicAdd(&deg[ei[N_EDGES + e]], 1);
}

__global__ __launch_bounds__(256) void scanA_kernel(const int* __restrict__ deg,
                                                    int* __restrict__ bsum) {
    __shared__ int s[256];
    int t = threadIdx.x;
    int n = blockIdx.x * 256 + t;
    s[t] = (n < N_NODES) ? deg[n] : 0;
    __syncthreads();
    for (int d = 128; d > 0; d >>= 1) {
        if (t < d) s[t] += s[t + d];
        __syncthreads();
    }
    if (t == 0) bsum[blockIdx.x] = s[0];
}

__global__ __launch_bounds__(512) void scanB_kernel(const int* __restrict__ bsum,
                                                    int* __restrict__ boff) {
    __shared__ int s[512];
    int t = threadIdx.x;
    s[t] = (t < NB_SCAN) ? bsum[t] : 0;
    __syncthreads();
    for (int d = 1; d < 512; d <<= 1) {
        int v = (t >= d) ? s[t - d] : 0;
        __syncthreads();
        s[t] += v;
        __syncthreads();
    }
    if (t < NB_SCAN) boff[t] = (t == 0) ? 0 : s[t - 1];
}

__global__ __launch_bounds__(256) void scanC_kernel(const int* __restrict__ deg,
                                                    const int* __restrict__ boff,
                                                    int* __restrict__ offs,
                                                    int* __restrict__ cursor) {
    __shared__ int s[256];
    int t = threadIdx.x;
    int n = blockIdx.x * 256 + t;
    int v = (n < N_NODES) ? deg[n] : 0;
    s[t] = v;
    __syncthreads();
    for (int d = 1; d < 256; d <<= 1) {
        int u = (t >= d) ? s[t - d] : 0;
        __syncthreads();
        s[t] += u;
        __syncthreads();
    }
    if (n < N_NODES) {
        int bo = boff[blockIdx.x];
        int excl = bo + s[t] - v;
        offs[n] = excl;
        cursor[n] = excl;
        if (n == N_NODES - 1) offs[N_NODES] = bo + s[t];
    }
}

// ---------------- place, dst-range partitioned (pass p: dst in [lo,hi)) ----------------
// csr writes for a pass land in a ~800 KB L2-resident window -> lines absorb
// all writes before writeback (kills the 16x write amplification of 1-pass place).
__global__ __launch_bounds__(256) void place_pass_kernel(const int* __restrict__ ei,
                                                         int* __restrict__ cursor,
                                                         int* __restrict__ csr,
                                                         int lo, int hi) {
    int e = blockIdx.x * 256 + threadIdx.x;
    if (e < N_EDGES) {
        int d = ei[N_EDGES + e];
        if (d >= lo && d < hi) {
            int pos = atomicAdd(&cursor[d], 1);
            csr[pos] = ei[e];
        }
    }
}

// ---------------- gather (bf16): agg[n] = h[n] + sum_{s in N(n)} h[s] ----------------
__global__ __launch_bounds__(256) void gather_kernel(const unsigned short* __restrict__ h,
                                                     const int* __restrict__ offs,
                                                     const int* __restrict__ csr,
                                                     unsigned short* __restrict__ agg) {
    int t = threadIdx.x;
    int node = blockIdx.x * 16 + (t >> 4);
    int q = t & 15;
    if (node >= N_NODES) return;
    int off0 = offs[node], off1 = offs[node + 1];
    float acc[8] = {0.f, 0.f, 0.f, 0.f, 0.f, 0.f, 0.f, 0.f};
    addrow(acc, *(const uint4*)(h + (size_t)node * HID + q * 8));
    int e = off0;
    for (; e + 8 <= off1; e += 8) {
        int s0 = csr[e], s1 = csr[e + 1], s2 = csr[e + 2], s3 = csr[e + 3];
        int s4 = csr[e + 4], s5 = csr[e + 5], s6 = csr[e + 6], s7 = csr[e + 7];
        uint4 w0 = *(const uint4*)(h + (size_t)s0 * HID + q * 8);
        uint4 w1 = *(const uint4*)(h + (size_t)s1 * HID + q * 8);
        uint4 w2 = *(const uint4*)(h + (size_t)s2 * HID + q * 8);
        uint4 w3 = *(const uint4*)(h + (size_t)s3 * HID + q * 8);
        uint4 w4 = *(const uint4*)(h + (size_t)s4 * HID + q * 8);
        uint4 w5 = *(const uint4*)(h + (size_t)s5 * HID + q * 8);
        uint4 w6 = *(const uint4*)(h + (size_t)s6 * HID + q * 8);
        uint4 w7 = *(const uint4*)(h + (size_t)s7 * HID + q * 8);
        addrow(acc, w0); addrow(acc, w1); addrow(acc, w2); addrow(acc, w3);
        addrow(acc, w4); addrow(acc, w5); addrow(acc, w6); addrow(acc, w7);
    }
    for (; e + 4 <= off1; e += 4) {
        int s0 = csr[e], s1 = csr[e + 1], s2 = csr[e + 2], s3 = csr[e + 3];
        uint4 w0 = *(const uint4*)(h + (size_t)s0 * HID + q * 8);
        uint4 w1 = *(const uint4*)(h + (size_t)s1 * HID + q * 8);
        uint4 w2 = *(const uint4*)(h + (size_t)s2 * HID + q * 8);
        uint4 w3 = *(const uint4*)(h + (size_t)s3 * HID + q * 8);
        addrow(acc, w0); addrow(acc, w1); addrow(acc, w2); addrow(acc, w3);
    }
    for (; e < off1; ++e) {
        addrow(acc, *(const uint4*)(h + (size_t)csr[e] * HID + q * 8));
    }
    uint4 o;
    o.x = pack2(acc[0], acc[1]);
    o.y = pack2(acc[2], acc[3]);
    o.z = pack2(acc[4], acc[5]);
    o.w = pack2(acc[6], acc[7]);
    *(uint4*)(agg + (size_t)node * HID + q * 8) = o;
}

// ---------------- MFMA MLP (round-5 proven) ----------------
__global__ __launch_bounds__(256) void mlp_kernel(const unsigned short* __restrict__ A,
                                                  const unsigned short* __restrict__ W1t,
                                                  const float* __restrict__ b1,
                                                  const unsigned short* __restrict__ W2t,
                                                  const float* __restrict__ b2,
                                                  unsigned short* __restrict__ out) {
    __shared__ unsigned short sA[64][136];  // row stride 272B = 17*16B
    __shared__ unsigned short sW[128][40];  // row stride 80B = 5*16B
    __shared__ float sb[128];
    const int t = threadIdx.x;
    const int w = t >> 6;
    const int l = t & 63;
    const int lm = l & 15;
    const int quad = l >> 4;
    const int row0 = blockIdx.x * 64;

    for (int idx = t; idx < 1024; idx += 256) {
        int r = idx >> 4, c = idx & 15;
        int grow = row0 + r;
        uint4 v = make_uint4(0u, 0u, 0u, 0u);
        if (grow < N_NODES) v = *(const uint4*)(A + (size_t)grow * HID + c * 8);
        *(uint4*)&sA[r][c * 8] = v;
    }

    const unsigned short* Wt[2] = {W1t, W2t};
    const float* bias[2] = {b1, b2};

    for (int p = 0; p < 2; ++p) {
        if (t < 128) sb[t] = bias[p][t];
        f32x4 acc[8];
#pragma unroll
        for (int nt = 0; nt < 8; ++nt) acc[nt] = (f32x4){0.f, 0.f, 0.f, 0.f};

        for (int kc = 0; kc < 4; ++kc) {
            __syncthreads();
            for (int idx = t; idx < 512; idx += 256) {
                int n = idx >> 2, kq = idx & 3;
                *(uint4*)&sW[n][kq * 8] =
                    *(const uint4*)(Wt[p] + (size_t)n * HID + kc * 32 + kq * 8);
            }
            __syncthreads();
            bf16x8 a = *(const bf16x8*)&sA[w * 16 + lm][kc * 32 + quad * 8];
#pragma unroll
            for (int nt = 0; nt < 8; ++nt) {
                bf16x8 b = *(const bf16x8*)&sW[nt * 16 + lm][quad * 8];
                acc[nt] = __builtin_amdgcn_mfma_f32_16x16x32_bf16(a, b, acc[nt], 0, 0, 0);
            }
        }
        __syncthreads();
#pragma unroll
        for (int nt = 0; nt < 8; ++nt) {
            float bv = sb[nt * 16 + lm];
#pragma unroll
            for (int r = 0; r < 4; ++r) {
                int m = w * 16 + quad * 4 + r;
                float val = fmaxf(acc[nt][r] + bv, 0.f);
                sA[m][nt * 16 + lm] = f2bf(val);
            }
        }
        __syncthreads();
    }
    for (int idx = t; idx < 1024; idx += 256) {
        int r = idx >> 4, c = idx & 15;
        int grow = row0 + r;
        if (grow < N_NODES)
            *(uint4*)(out + (size_t)grow * HID + c * 8) = *(const uint4*)&sA[r][c * 8];
    }
}

// ---------------- pool: g[batch[n]] += h[n] (batch sorted, bf16 in, fp32 out) ----------------
__global__ __launch_bounds__(128) void pool_kernel(const unsigned short* __restrict__ h,
                                                   const int* __restrict__ batch,
                                                   float* __restrict__ g) {
    const int CHUNK = 256;
    int c = threadIdx.x;
    int n0 = blockIdx.x * CHUNK;
    if (n0 >= N_NODES) return;
    int n1 = n0 + CHUNK;
    if (n1 > N_NODES) n1 = N_NODES;
    int cur = batch[n0];
    float acc = 0.f;
    for (int n = n0; n < n1; ++n) {
        int b = batch[n];
        if (b != cur) {
            atomicAdd(&g[(size_t)cur * HID + c], acc);
            acc = 0.f;
            cur = b;
        }
        acc += bf2f(h[(size_t)n * HID + c]);
    }
    atomicAdd(&g[(size_t)cur * HID + c], acc);
}

// ---------------- heads ----------------
__global__ __launch_bounds__(128) void head_kernel(const float* __restrict__ g,
                                                   const float* __restrict__ Wmu,
                                                   const float* __restrict__ bmu,
                                                   const float* __restrict__ Wlv,
                                                   const float* __restrict__ blv,
                                                   float* __restrict__ out) {
    __shared__ float sg[HID];
    int gi = blockIdx.x;
    sg[threadIdx.x] = g[(size_t)gi * HID + threadIdx.x];
    __syncthreads();
    int j = threadIdx.x & 63;
    bool is_lv = threadIdx.x >= 64;
    const float* W = is_lv ? Wlv : Wmu;
    float acc = is_lv ? blv[j] : bmu[j];
    for (int k = 0; k < HID; ++k) acc = fmaf(sg[k], W[k * LAT + j], acc);
    out[(is_lv ? (size_t)N_GRAPHS * LAT : 0) + (size_t)gi * LAT + j] = acc;
}

extern "C" void kernel_launch(void* const* d_in, const int* in_sizes, int n_in,
                              void* d_out, int out_size, void* d_ws, size_t ws_size,
                              hipStream_t stream) {
    const float* x     = (const float*)d_in[0];
    const int*   ei    = (const int*)d_in[1];
    const int*   batch = (const int*)d_in[2];
    const float* W1    = (const float*)d_in[3];
    const float* b1    = (const float*)d_in[4];
    const float* W2    = (const float*)d_in[5];
    const float* b2    = (const float*)d_in[6];
    const float* Wmu   = (const float*)d_in[7];
    const float* bmu   = (const float*)d_in[8];
    const float* Wlv   = (const float*)d_in[9];
    const float* blv   = (const float*)d_in[10];
    float* out = (float*)d_out;

    float* g = (float*)d_ws;
    unsigned short* xb   = (unsigned short*)(g + (size_t)N_GRAPHS * HID);
    unsigned short* agg  = xb + (size_t)N_NODES * HID;
    unsigned short* hbuf = agg + (size_t)N_NODES * HID;
    unsigned short* Wt   = hbuf + (size_t)N_NODES * HID;
    int* deg    = (int*)(Wt + (size_t)6 * HID * HID);
    int* offs   = deg + N_NODES;
    int* cursor = offs + N_NODES + 1;
    int* bsum   = cursor + N_NODES;
    int* boff   = bsum + NB_SCAN;
    int* csr    = boff + NB_SCAN + 1;               // 6.4 MB

    // ---- CSR build ----
    hipMemsetAsync(deg, 0, (size_t)N_NODES * sizeof(int), stream);
    count_kernel<<<(N_EDGES + 255) / 256, 256, 0, stream>>>(ei, deg);
    scanA_kernel<<<NB_SCAN, 256, 0, stream>>>(deg, bsum);
    scanB_kernel<<<1, 512, 0, stream>>>(bsum, boff);
    scanC_kernel<<<NB_SCAN, 256, 0, stream>>>(deg, boff, offs, cursor);
    for (int p = 0; p < N_PASS; ++p) {
        int lo = p * PASS_W;
        int hi = lo + PASS_W;
        if (hi > N_NODES) hi = N_NODES;
        place_pass_kernel<<<(N_EDGES + 255) / 256, 256, 0, stream>>>(ei, cursor, csr, lo, hi);
    }

    // ---- prep bf16 ----
    cvt_x_kernel<<<(N_NODES * HID / 4 + 255) / 256, 256, 0, stream>>>(x, xb,
                                                                      N_NODES * HID / 4);
    wt_kernel<<<6, 256, 0, stream>>>(W1, W2, Wt);

    const unsigned short* hcur = xb;
    for (int i = 0; i < N_LAYERS; ++i) {
        gather_kernel<<<(N_NODES + 15) / 16, 256, 0, stream>>>(hcur, offs, csr, agg);
        mlp_kernel<<<(N_NODES + 63) / 64, 256, 0, stream>>>(
            agg, Wt + (size_t)(2 * i) * HID * HID, b1 + (size_t)i * HID,
            Wt + (size_t)(2 * i + 1) * HID * HID, b2 + (size_t)i * HID, hbuf);
        hcur = hbuf;
    }
    hipMemsetAsync(g, 0, (size_t)N_GRAPHS * HID * sizeof(float), stream);
    pool_kernel<<<(N_NODES + 255) / 256, 128, 0, stream>>>(hcur, batch, g);
    head_kernel<<<N_GRAPHS, 128, 0, stream>>>(g, Wmu, bmu, Wlv, blv, out);
}

// Round 9
// 588.627 us; speedup vs baseline: 1.3761x; 1.0860x over previous
//
#include <hip/hip_runtime.h>

#define N_NODES 100000
#define N_EDGES 1600000
#define HID 128
#define LAT 64
#define N_LAYERS 3
#define N_GRAPHS 1000
#define NB_SCAN ((N_NODES + 255) / 256)   // 391
#define N_PASS 4
#define PASS_W ((N_NODES + N_PASS - 1) / N_PASS)  // 25000

typedef short bf16x8 __attribute__((ext_vector_type(8)));
typedef float f32x4 __attribute__((ext_vector_type(4)));

__device__ __forceinline__ float bf2f(unsigned short h) {
    union { unsigned int u; float f; } c;
    c.u = ((unsigned int)h) << 16;
    return c.f;
}
__device__ __forceinline__ unsigned short f2bf(float f) {
    union { float f; unsigned int u; } c;
    c.f = f;
    unsigned int u = c.u;
    return (unsigned short)((u + 0x7fffu + ((u >> 16) & 1u)) >> 16);
}
__device__ __forceinline__ unsigned int pack2(float a, float b) {
    return (unsigned int)f2bf(a) | ((unsigned int)f2bf(b) << 16);
}
__device__ __forceinline__ void addrow(float* acc, uint4 w) {
    acc[0] += bf2f((unsigned short)w.x); acc[1] += bf2f((unsigned short)(w.x >> 16));
    acc[2] += bf2f((unsigned short)w.y); acc[3] += bf2f((unsigned short)(w.y >> 16));
    acc[4] += bf2f((unsigned short)w.z); acc[5] += bf2f((unsigned short)(w.z >> 16));
    acc[6] += bf2f((unsigned short)w.w); acc[7] += bf2f((unsigned short)(w.w >> 16));
}

// ---------------- convert x fp32 -> bf16 ----------------
__global__ __launch_bounds__(256) void cvt_x_kernel(const float* __restrict__ x,
                                                    unsigned short* __restrict__ xb, int n4) {
    int i = blockIdx.x * 256 + threadIdx.x;
    if (i >= n4) return;
    float4 v = ((const float4*)x)[i];
    ((uint2*)xb)[i] = make_uint2(pack2(v.x, v.y), pack2(v.z, v.w));
}

// ---------------- W [k][n] fp32 -> Wt [n][k] bf16, 6 matrices ----------------
__global__ __launch_bounds__(256) void wt_kernel(const float* __restrict__ W1,
                                                 const float* __restrict__ W2,
                                                 unsigned short* __restrict__ Wt) {
    int m = blockIdx.x;  // 0..5 : layer*2 + phase
    const float* W = ((m & 1) ? W2 : W1) + (size_t)(m >> 1) * HID * HID;
    unsigned short* D = Wt + (size_t)m * HID * HID;
    for (int idx = threadIdx.x; idx < HID * HID; idx += 256) {
        int n = idx >> 7, k = idx & 127;
        D[n * HID + k] = f2bf(W[k * HID + n]);
    }
}

// ---------------- CSR build ----------------
__global__ __launch_bounds__(256) void count_kernel(const int* __restrict__ ei,
                                                    int* __restrict__ deg) {
    int e = blockIdx.x * 256 + threadIdx.x;
    if (e < N_EDGES) atomicAdd(&deg[ei[N_EDGES + e]], 1);
}

__global__ __launch_bounds__(256) void scanA_kernel(const int* __restrict__ deg,
                                                    int* __restrict__ bsum) {
    __shared__ int s[256];
    int t = threadIdx.x;
    int n = blockIdx.x * 256 + t;
    s[t] = (n < N_NODES) ? deg[n] : 0;
    __syncthreads();
    for (int d = 128; d > 0; d >>= 1) {
        if (t < d) s[t] += s[t + d];
        __syncthreads();
    }
    if (t == 0) bsum[blockIdx.x] = s[0];
}

__global__ __launch_bounds__(512) void scanB_kernel(const int* __restrict__ bsum,
                                                    int* __restrict__ boff) {
    __shared__ int s[512];
    int t = threadIdx.x;
    s[t] = (t < NB_SCAN) ? bsum[t] : 0;
    __syncthreads();
    for (int d = 1; d < 512; d <<= 1) {
        int v = (t >= d) ? s[t - d] : 0;
        __syncthreads();
        s[t] += v;
        __syncthreads();
    }
    if (t < NB_SCAN) boff[t] = (t == 0) ? 0 : s[t - 1];
}

__global__ __launch_bounds__(256) void scanC_kernel(const int* __restrict__ deg,
                                                    const int* __restrict__ boff,
                                                    int* __restrict__ offs,
                                                    int* __restrict__ cursor) {
    __shared__ int s[256];
    int t = threadIdx.x;
    int n = blockIdx.x * 256 + t;
    int v = (n < N_NODES) ? deg[n] : 0;
    s[t] = v;
    __syncthreads();
    for (int d = 1; d < 256; d <<= 1) {
        int u = (t >= d) ? s[t - d] : 0;
        __syncthreads();
        s[t] += u;
        __syncthreads();
    }
    if (n < N_NODES) {
        int bo = boff[blockIdx.x];
        int excl = bo + s[t] - v;
        offs[n] = excl;
        cursor[n] = excl;
        if (n == N_NODES - 1) offs[N_NODES] = bo + s[t];
    }
}

// ---------------- place, dst-range partitioned ----------------
__global__ __launch_bounds__(256) void place_pass_kernel(const int* __restrict__ ei,
                                                         int* __restrict__ cursor,
                                                         int* __restrict__ csr,
                                                         int lo, int hi) {
    int e = blockIdx.x * 256 + threadIdx.x;
    if (e < N_EDGES) {
        int d = ei[N_EDGES + e];
        if (d >= lo && d < hi) {
            int pos = atomicAdd(&cursor[d], 1);
            csr[pos] = ei[e];
        }
    }
}

// ---------------- gather (bf16): agg[n] = h[n] + sum_{s in N(n)} h[s] ----------------
__global__ __launch_bounds__(256) void gather_kernel(const unsigned short* __restrict__ h,
                                                     const int* __restrict__ offs,
                                                     const int* __restrict__ csr,
                                                     unsigned short* __restrict__ agg) {
    int t = threadIdx.x;
    int node = blockIdx.x * 16 + (t >> 4);
    int q = t & 15;
    if (node >= N_NODES) return;
    int off0 = offs[node], off1 = offs[node + 1];
    float acc[8] = {0.f, 0.f, 0.f, 0.f, 0.f, 0.f, 0.f, 0.f};
    addrow(acc, *(const uint4*)(h + (size_t)node * HID + q * 8));
    int e = off0;
    for (; e + 8 <= off1; e += 8) {
        int s0 = csr[e], s1 = csr[e + 1], s2 = csr[e + 2], s3 = csr[e + 3];
        int s4 = csr[e + 4], s5 = csr[e + 5], s6 = csr[e + 6], s7 = csr[e + 7];
        uint4 w0 = *(const uint4*)(h + (size_t)s0 * HID + q * 8);
        uint4 w1 = *(const uint4*)(h + (size_t)s1 * HID + q * 8);
        uint4 w2 = *(const uint4*)(h + (size_t)s2 * HID + q * 8);
        uint4 w3 = *(const uint4*)(h + (size_t)s3 * HID + q * 8);
        uint4 w4 = *(const uint4*)(h + (size_t)s4 * HID + q * 8);
        uint4 w5 = *(const uint4*)(h + (size_t)s5 * HID + q * 8);
        uint4 w6 = *(const uint4*)(h + (size_t)s6 * HID + q * 8);
        uint4 w7 = *(const uint4*)(h + (size_t)s7 * HID + q * 8);
        addrow(acc, w0); addrow(acc, w1); addrow(acc, w2); addrow(acc, w3);
        addrow(acc, w4); addrow(acc, w5); addrow(acc, w6); addrow(acc, w7);
    }
    for (; e + 4 <= off1; e += 4) {
        int s0 = csr[e], s1 = csr[e + 1], s2 = csr[e + 2], s3 = csr[e + 3];
        uint4 w0 = *(const uint4*)(h + (size_t)s0 * HID + q * 8);
        uint4 w1 = *(const uint4*)(h + (size_t)s1 * HID + q * 8);
        uint4 w2 = *(const uint4*)(h + (size_t)s2 * HID + q * 8);
        uint4 w3 = *(const uint4*)(h + (size_t)s3 * HID + q * 8);
        addrow(acc, w0); addrow(acc, w1); addrow(acc, w2); addrow(acc, w3);
    }
    for (; e < off1; ++e) {
        addrow(acc, *(const uint4*)(h + (size_t)csr[e] * HID + q * 8));
    }
    uint4 o;
    o.x = pack2(acc[0], acc[1]);
    o.y = pack2(acc[2], acc[3]);
    o.z = pack2(acc[4], acc[5]);
    o.w = pack2(acc[6], acc[7]);
    *(uint4*)(agg + (size_t)node * HID + q * 8) = o;
}

// ---------------- MFMA MLP (round-5 proven) ----------------
__global__ __launch_bounds__(256) void mlp_kernel(const unsigned short* __restrict__ A,
                                                  const unsigned short* __restrict__ W1t,
                                                  const float* __restrict__ b1,
                                                  const unsigned short* __restrict__ W2t,
                                                  const float* __restrict__ b2,
                                                  unsigned short* __restrict__ out) {
    __shared__ unsigned short sA[64][136];  // row stride 272B = 17*16B
    __shared__ unsigned short sW[128][40];  // row stride 80B = 5*16B
    __shared__ float sb[128];
    const int t = threadIdx.x;
    const int w = t >> 6;
    const int l = t & 63;
    const int lm = l & 15;
    const int quad = l >> 4;
    const int row0 = blockIdx.x * 64;

    for (int idx = t; idx < 1024; idx += 256) {
        int r = idx >> 4, c = idx & 15;
        int grow = row0 + r;
        uint4 v = make_uint4(0u, 0u, 0u, 0u);
        if (grow < N_NODES) v = *(const uint4*)(A + (size_t)grow * HID + c * 8);
        *(uint4*)&sA[r][c * 8] = v;
    }

    const unsigned short* Wt[2] = {W1t, W2t};
    const float* bias[2] = {b1, b2};

    for (int p = 0; p < 2; ++p) {
        if (t < 128) sb[t] = bias[p][t];
        f32x4 acc[8];
#pragma unroll
        for (int nt = 0; nt < 8; ++nt) acc[nt] = (f32x4){0.f, 0.f, 0.f, 0.f};

        for (int kc = 0; kc < 4; ++kc) {
            __syncthreads();
            for (int idx = t; idx < 512; idx += 256) {
                int n = idx >> 2, kq = idx & 3;
                *(uint4*)&sW[n][kq * 8] =
                    *(const uint4*)(Wt[p] + (size_t)n * HID + kc * 32 + kq * 8);
            }
            __syncthreads();
            bf16x8 a = *(const bf16x8*)&sA[w * 16 + lm][kc * 32 + quad * 8];
#pragma unroll
            for (int nt = 0; nt < 8; ++nt) {
                bf16x8 b = *(const bf16x8*)&sW[nt * 16 + lm][quad * 8];
                acc[nt] = __builtin_amdgcn_mfma_f32_16x16x32_bf16(a, b, acc[nt], 0, 0, 0);
            }
        }
        __syncthreads();
#pragma unroll
        for (int nt = 0; nt < 8; ++nt) {
            float bv = sb[nt * 16 + lm];
#pragma unroll
            for (int r = 0; r < 4; ++r) {
                int m = w * 16 + quad * 4 + r;
                float val = fmaxf(acc[nt][r] + bv, 0.f);
                sA[m][nt * 16 + lm] = f2bf(val);
            }
        }
        __syncthreads();
    }
    for (int idx = t; idx < 1024; idx += 256) {
        int r = idx >> 4, c = idx & 15;
        int grow = row0 + r;
        if (grow < N_NODES)
            *(uint4*)(out + (size_t)grow * HID + c * 8) = *(const uint4*)&sA[r][c * 8];
    }
}

// ---------------- pool: g[batch[n]] += h[n] (batch sorted, bf16 in, fp32 out) ----------------
// 16-lane group owns 8 channels/lane (uint4); 16 nodes per group; fp32 regs,
// flush on graph change via atomics into L2-resident g.
__global__ __launch_bounds__(256) void pool_kernel(const unsigned short* __restrict__ h,
                                                   const int* __restrict__ batch,
                                                   float* __restrict__ g) {
    const int S = 16;  // nodes per 16-lane group
    int t = threadIdx.x;
    int grp = t >> 4;   // 0..15
    int q = t & 15;     // channel octet
    int n0 = (blockIdx.x * 16 + grp) * S;
    if (n0 >= N_NODES) return;
    int n1 = n0 + S;
    if (n1 > N_NODES) n1 = N_NODES;
    int cur = batch[n0];
    float acc[8] = {0.f, 0.f, 0.f, 0.f, 0.f, 0.f, 0.f, 0.f};
    for (int n = n0; n < n1; ++n) {
        int b = batch[n];
        if (b != cur) {
            float* gp = g + (size_t)cur * HID + q * 8;
#pragma unroll
            for (int i = 0; i < 8; ++i) { atomicAdd(gp + i, acc[i]); acc[i] = 0.f; }
            cur = b;
        }
        addrow(acc, *(const uint4*)(h + (size_t)n * HID + q * 8));
    }
    float* gp = g + (size_t)cur * HID + q * 8;
#pragma unroll
    for (int i = 0; i < 8; ++i) atomicAdd(gp + i, acc[i]);
}

// ---------------- heads ----------------
__global__ __launch_bounds__(128) void head_kernel(const float* __restrict__ g,
                                                   const float* __restrict__ Wmu,
                                                   const float* __restrict__ bmu,
                                                   const float* __restrict__ Wlv,
                                                   const float* __restrict__ blv,
                                                   float* __restrict__ out) {
    __shared__ float sg[HID];
    int gi = blockIdx.x;
    sg[threadIdx.x] = g[(size_t)gi * HID + threadIdx.x];
    __syncthreads();
    int j = threadIdx.x & 63;
    bool is_lv = threadIdx.x >= 64;
    const float* W = is_lv ? Wlv : Wmu;
    float acc = is_lv ? blv[j] : bmu[j];
    for (int k = 0; k < HID; ++k) acc = fmaf(sg[k], W[k * LAT + j], acc);
    out[(is_lv ? (size_t)N_GRAPHS * LAT : 0) + (size_t)gi * LAT + j] = acc;
}

extern "C" void kernel_launch(void* const* d_in, const int* in_sizes, int n_in,
                              void* d_out, int out_size, void* d_ws, size_t ws_size,
                              hipStream_t stream) {
    const float* x     = (const float*)d_in[0];
    const int*   ei    = (const int*)d_in[1];
    const int*   batch = (const int*)d_in[2];
    const float* W1    = (const float*)d_in[3];
    const float* b1    = (const float*)d_in[4];
    const float* W2    = (const float*)d_in[5];
    const float* b2    = (const float*)d_in[6];
    const float* Wmu   = (const float*)d_in[7];
    const float* bmu   = (const float*)d_in[8];
    const float* Wlv   = (const float*)d_in[9];
    const float* blv   = (const float*)d_in[10];
    float* out = (float*)d_out;

    float* g = (float*)d_ws;
    unsigned short* xb   = (unsigned short*)(g + (size_t)N_GRAPHS * HID);
    unsigned short* agg  = xb + (size_t)N_NODES * HID;
    unsigned short* hbuf = agg + (size_t)N_NODES * HID;
    unsigned short* Wt   = hbuf + (size_t)N_NODES * HID;
    int* deg    = (int*)(Wt + (size_t)6 * HID * HID);
    int* offs   = deg + N_NODES;
    int* cursor = offs + N_NODES + 1;
    int* bsum   = cursor + N_NODES;
    int* boff   = bsum + NB_SCAN;
    int* csr    = boff + NB_SCAN + 1;               // 6.4 MB

    // ---- CSR build ----
    hipMemsetAsync(deg, 0, (size_t)N_NODES * sizeof(int), stream);
    count_kernel<<<(N_EDGES + 255) / 256, 256, 0, stream>>>(ei, deg);
    scanA_kernel<<<NB_SCAN, 256, 0, stream>>>(deg, bsum);
    scanB_kernel<<<1, 512, 0, stream>>>(bsum, boff);
    scanC_kernel<<<NB_SCAN, 256, 0, stream>>>(deg, boff, offs, cursor);
    for (int p = 0; p < N_PASS; ++p) {
        int lo = p * PASS_W;
        int hi = lo + PASS_W;
        if (hi > N_NODES) hi = N_NODES;
        place_pass_kernel<<<(N_EDGES + 255) / 256, 256, 0, stream>>>(ei, cursor, csr, lo, hi);
    }

    // ---- prep bf16 ----
    cvt_x_kernel<<<(N_NODES * HID / 4 + 255) / 256, 256, 0, stream>>>(x, xb,
                                                                      N_NODES * HID / 4);
    wt_kernel<<<6, 256, 0, stream>>>(W1, W2, Wt);

    const unsigned short* hcur = xb;
    for (int i = 0; i < N_LAYERS; ++i) {
        gather_kernel<<<(N_NODES + 15) / 16, 256, 0, stream>>>(hcur, offs, csr, agg);
        mlp_kernel<<<(N_NODES + 63) / 64, 256, 0, stream>>>(
            agg, Wt + (size_t)(2 * i) * HID * HID, b1 + (size_t)i * HID,
            Wt + (size_t)(2 * i + 1) * HID * HID, b2 + (size_t)i * HID, hbuf);
        hcur = hbuf;
    }
    hipMemsetAsync(g, 0, (size_t)N_GRAPHS * HID * sizeof(float), stream);
    pool_kernel<<<(N_NODES + 255) / 256, 256, 0, stream>>>(hcur, batch, g);
    head_kernel<<<N_GRAPHS, 128, 0, stream>>>(g, Wmu, bmu, Wlv, blv, out);
}

// Round 10
// 536.324 us; speedup vs baseline: 1.5103x; 1.0975x over previous
//
#include <hip/hip_runtime.h>

#define N_NODES 100000
#define N_EDGES 1600000
#define HID 128
#define LAT 64
#define N_LAYERS 3
#define N_GRAPHS 1000
#define CAP 64                                     // slots per node (P(deg>=64)~1e-19)
#define N_PASS 8
#define PASS_W ((N_NODES + N_PASS - 1) / N_PASS)   // 12500

typedef short bf16x8 __attribute__((ext_vector_type(8)));
typedef float f32x4 __attribute__((ext_vector_type(4)));

__device__ __forceinline__ float bf2f(unsigned short h) {
    union { unsigned int u; float f; } c;
    c.u = ((unsigned int)h) << 16;
    return c.f;
}
__device__ __forceinline__ unsigned short f2bf(float f) {
    union { float f; unsigned int u; } c;
    c.f = f;
    unsigned int u = c.u;
    return (unsigned short)((u + 0x7fffu + ((u >> 16) & 1u)) >> 16);
}
__device__ __forceinline__ unsigned int pack2(float a, float b) {
    return (unsigned int)f2bf(a) | ((unsigned int)f2bf(b) << 16);
}
__device__ __forceinline__ void addrow(float* acc, uint4 w) {
    acc[0] += bf2f((unsigned short)w.x); acc[1] += bf2f((unsigned short)(w.x >> 16));
    acc[2] += bf2f((unsigned short)w.y); acc[3] += bf2f((unsigned short)(w.y >> 16));
    acc[4] += bf2f((unsigned short)w.z); acc[5] += bf2f((unsigned short)(w.z >> 16));
    acc[6] += bf2f((unsigned short)w.w); acc[7] += bf2f((unsigned short)(w.w >> 16));
}

// ---------------- convert x fp32 -> bf16 ----------------
__global__ __launch_bounds__(256) void cvt_x_kernel(const float* __restrict__ x,
                                                    unsigned short* __restrict__ xb, int n4) {
    int i = blockIdx.x * 256 + threadIdx.x;
    if (i >= n4) return;
    float4 v = ((const float4*)x)[i];
    ((uint2*)xb)[i] = make_uint2(pack2(v.x, v.y), pack2(v.z, v.w));
}

// ---------------- W [k][n] fp32 -> Wt [n][k] bf16, 6 matrices ----------------
__global__ __launch_bounds__(256) void wt_kernel(const float* __restrict__ W1,
                                                 const float* __restrict__ W2,
                                                 unsigned short* __restrict__ Wt) {
    int m = blockIdx.x;  // 0..5 : layer*2 + phase
    const float* W = ((m & 1) ? W2 : W1) + (size_t)(m >> 1) * HID * HID;
    unsigned short* D = Wt + (size_t)m * HID * HID;
    for (int idx = threadIdx.x; idx < HID * HID; idx += 256) {
        int n = idx >> 7, k = idx & 127;
        D[n * HID + k] = f2bf(W[k * HID + n]);
    }
}

// ---------------- fixed-slot place, dst-range partitioned ----------------
// csr[d*CAP + cnt[d]++] = src. Pass p handles dst in [lo,hi): csr writes land
// in a 3.2 MB L2-resident window (kills write amplification); the cnt atomics
// double as the degree count — no separate count/scan kernels.
__global__ __launch_bounds__(256) void place_pass_kernel(const int* __restrict__ ei,
                                                         int* __restrict__ cnt,
                                                         int* __restrict__ csr,
                                                         int lo, int hi) {
    int e = blockIdx.x * 256 + threadIdx.x;
    if (e < N_EDGES) {
        int d = ei[N_EDGES + e];
        if (d >= lo && d < hi) {
            int c = atomicAdd(&cnt[d], 1);
            csr[(size_t)d * CAP + c] = ei[e];
        }
    }
}

// ---------------- gather (bf16): agg[n] = h[n] + sum_{s in N(n)} h[s] ----------------
__global__ __launch_bounds__(256) void gather_kernel(const unsigned short* __restrict__ h,
                                                     const int* __restrict__ cnt,
                                                     const int* __restrict__ csr,
                                                     unsigned short* __restrict__ agg) {
    int t = threadIdx.x;
    int node = blockIdx.x * 16 + (t >> 4);
    int q = t & 15;
    if (node >= N_NODES) return;
    const int* nl = csr + (size_t)node * CAP;
    int deg = cnt[node];
    float acc[8] = {0.f, 0.f, 0.f, 0.f, 0.f, 0.f, 0.f, 0.f};
    addrow(acc, *(const uint4*)(h + (size_t)node * HID + q * 8));
    int e = 0;
    for (; e + 8 <= deg; e += 8) {
        int s0 = nl[e], s1 = nl[e + 1], s2 = nl[e + 2], s3 = nl[e + 3];
        int s4 = nl[e + 4], s5 = nl[e + 5], s6 = nl[e + 6], s7 = nl[e + 7];
        uint4 w0 = *(const uint4*)(h + (size_t)s0 * HID + q * 8);
        uint4 w1 = *(const uint4*)(h + (size_t)s1 * HID + q * 8);
        uint4 w2 = *(const uint4*)(h + (size_t)s2 * HID + q * 8);
        uint4 w3 = *(const uint4*)(h + (size_t)s3 * HID + q * 8);
        uint4 w4 = *(const uint4*)(h + (size_t)s4 * HID + q * 8);
        uint4 w5 = *(const uint4*)(h + (size_t)s5 * HID + q * 8);
        uint4 w6 = *(const uint4*)(h + (size_t)s6 * HID + q * 8);
        uint4 w7 = *(const uint4*)(h + (size_t)s7 * HID + q * 8);
        addrow(acc, w0); addrow(acc, w1); addrow(acc, w2); addrow(acc, w3);
        addrow(acc, w4); addrow(acc, w5); addrow(acc, w6); addrow(acc, w7);
    }
    for (; e + 4 <= deg; e += 4) {
        int s0 = nl[e], s1 = nl[e + 1], s2 = nl[e + 2], s3 = nl[e + 3];
        uint4 w0 = *(const uint4*)(h + (size_t)s0 * HID + q * 8);
        uint4 w1 = *(const uint4*)(h + (size_t)s1 * HID + q * 8);
        uint4 w2 = *(const uint4*)(h + (size_t)s2 * HID + q * 8);
        uint4 w3 = *(const uint4*)(h + (size_t)s3 * HID + q * 8);
        addrow(acc, w0); addrow(acc, w1); addrow(acc, w2); addrow(acc, w3);
    }
    for (; e < deg; ++e) {
        addrow(acc, *(const uint4*)(h + (size_t)nl[e] * HID + q * 8));
    }
    uint4 o;
    o.x = pack2(acc[0], acc[1]);
    o.y = pack2(acc[2], acc[3]);
    o.z = pack2(acc[4], acc[5]);
    o.w = pack2(acc[6], acc[7]);
    *(uint4*)(agg + (size_t)node * HID + q * 8) = o;
}

// ---------------- MFMA MLP (round-5 proven) ----------------
__global__ __launch_bounds__(256) void mlp_kernel(const unsigned short* __restrict__ A,
                                                  const unsigned short* __restrict__ W1t,
                                                  const float* __restrict__ b1,
                                                  const unsigned short* __restrict__ W2t,
                                                  const float* __restrict__ b2,
                                                  unsigned short* __restrict__ out) {
    __shared__ unsigned short sA[64][136];  // row stride 272B = 17*16B
    __shared__ unsigned short sW[128][40];  // row stride 80B = 5*16B
    __shared__ float sb[128];
    const int t = threadIdx.x;
    const int w = t >> 6;
    const int l = t & 63;
    const int lm = l & 15;
    const int quad = l >> 4;
    const int row0 = blockIdx.x * 64;

    for (int idx = t; idx < 1024; idx += 256) {
        int r = idx >> 4, c = idx & 15;
        int grow = row0 + r;
        uint4 v = make_uint4(0u, 0u, 0u, 0u);
        if (grow < N_NODES) v = *(const uint4*)(A + (size_t)grow * HID + c * 8);
        *(uint4*)&sA[r][c * 8] = v;
    }

    const unsigned short* Wt[2] = {W1t, W2t};
    const float* bias[2] = {b1, b2};

    for (int p = 0; p < 2; ++p) {
        if (t < 128) sb[t] = bias[p][t];
        f32x4 acc[8];
#pragma unroll
        for (int nt = 0; nt < 8; ++nt) acc[nt] = (f32x4){0.f, 0.f, 0.f, 0.f};

        for (int kc = 0; kc < 4; ++kc) {
            __syncthreads();
            for (int idx = t; idx < 512; idx += 256) {
                int n = idx >> 2, kq = idx & 3;
                *(uint4*)&sW[n][kq * 8] =
                    *(const uint4*)(Wt[p] + (size_t)n * HID + kc * 32 + kq * 8);
            }
            __syncthreads();
            bf16x8 a = *(const bf16x8*)&sA[w * 16 + lm][kc * 32 + quad * 8];
#pragma unroll
            for (int nt = 0; nt < 8; ++nt) {
                bf16x8 b = *(const bf16x8*)&sW[nt * 16 + lm][quad * 8];
                acc[nt] = __builtin_amdgcn_mfma_f32_16x16x32_bf16(a, b, acc[nt], 0, 0, 0);
            }
        }
        __syncthreads();
#pragma unroll
        for (int nt = 0; nt < 8; ++nt) {
            float bv = sb[nt * 16 + lm];
#pragma unroll
            for (int r = 0; r < 4; ++r) {
                int m = w * 16 + quad * 4 + r;
                float val = fmaxf(acc[nt][r] + bv, 0.f);
                sA[m][nt * 16 + lm] = f2bf(val);
            }
        }
        __syncthreads();
    }
    for (int idx = t; idx < 1024; idx += 256) {
        int r = idx >> 4, c = idx & 15;
        int grow = row0 + r;
        if (grow < N_NODES)
            *(uint4*)(out + (size_t)grow * HID + c * 8) = *(const uint4*)&sA[r][c * 8];
    }
}

// ---------------- pool (round-9 proven) ----------------
__global__ __launch_bounds__(256) void pool_kernel(const unsigned short* __restrict__ h,
                                                   const int* __restrict__ batch,
                                                   float* __restrict__ g) {
    const int S = 16;  // nodes per 16-lane group
    int t = threadIdx.x;
    int grp = t >> 4;
    int q = t & 15;
    int n0 = (blockIdx.x * 16 + grp) * S;
    if (n0 >= N_NODES) return;
    int n1 = n0 + S;
    if (n1 > N_NODES) n1 = N_NODES;
    int cur = batch[n0];
    float acc[8] = {0.f, 0.f, 0.f, 0.f, 0.f, 0.f, 0.f, 0.f};
    for (int n = n0; n < n1; ++n) {
        int b = batch[n];
        if (b != cur) {
            float* gp = g + (size_t)cur * HID + q * 8;
#pragma unroll
            for (int i = 0; i < 8; ++i) { atomicAdd(gp + i, acc[i]); acc[i] = 0.f; }
            cur = b;
        }
        addrow(acc, *(const uint4*)(h + (size_t)n * HID + q * 8));
    }
    float* gp = g + (size_t)cur * HID + q * 8;
#pragma unroll
    for (int i = 0; i < 8; ++i) atomicAdd(gp + i, acc[i]);
}

// ---------------- heads ----------------
__global__ __launch_bounds__(128) void head_kernel(const float* __restrict__ g,
                                                   const float* __restrict__ Wmu,
                                                   const float* __restrict__ bmu,
                                                   const float* __restrict__ Wlv,
                                                   const float* __restrict__ blv,
                                                   float* __restrict__ out) {
    __shared__ float sg[HID];
    int gi = blockIdx.x;
    sg[threadIdx.x] = g[(size_t)gi * HID + threadIdx.x];
    __syncthreads();
    int j = threadIdx.x & 63;
    bool is_lv = threadIdx.x >= 64;
    const float* W = is_lv ? Wlv : Wmu;
    float acc = is_lv ? blv[j] : bmu[j];
    for (int k = 0; k < HID; ++k) acc = fmaf(sg[k], W[k * LAT + j], acc);
    out[(is_lv ? (size_t)N_GRAPHS * LAT : 0) + (size_t)gi * LAT + j] = acc;
}

extern "C" void kernel_launch(void* const* d_in, const int* in_sizes, int n_in,
                              void* d_out, int out_size, void* d_ws, size_t ws_size,
                              hipStream_t stream) {
    const float* x     = (const float*)d_in[0];
    const int*   ei    = (const int*)d_in[1];
    const int*   batch = (const int*)d_in[2];
    const float* W1    = (const float*)d_in[3];
    const float* b1    = (const float*)d_in[4];
    const float* W2    = (const float*)d_in[5];
    const float* b2    = (const float*)d_in[6];
    const float* Wmu   = (const float*)d_in[7];
    const float* bmu   = (const float*)d_in[8];
    const float* Wlv   = (const float*)d_in[9];
    const float* blv   = (const float*)d_in[10];
    float* out = (float*)d_out;

    float* g = (float*)d_ws;                                       // 512 KB
    unsigned short* xb   = (unsigned short*)(g + (size_t)N_GRAPHS * HID);
    unsigned short* agg  = xb + (size_t)N_NODES * HID;             // 25.6 MB each
    unsigned short* hbuf = agg + (size_t)N_NODES * HID;
    unsigned short* Wt   = hbuf + (size_t)N_NODES * HID;           // 192 KB
    int* cnt = (int*)(Wt + (size_t)6 * HID * HID);                 // 400 KB
    int* csr = cnt + N_NODES;                                      // 25.6 MB

    // ---- CSR build: fixed-slot, 8 dst-partitioned passes ----
    hipMemsetAsync(cnt, 0, (size_t)N_NODES * sizeof(int), stream);
    for (int p = 0; p < N_PASS; ++p) {
        int lo = p * PASS_W;
        int hi = lo + PASS_W;
        if (hi > N_NODES) hi = N_NODES;
        place_pass_kernel<<<(N_EDGES + 255) / 256, 256, 0, stream>>>(ei, cnt, csr, lo, hi);
    }

    // ---- prep bf16 ----
    cvt_x_kernel<<<(N_NODES * HID / 4 + 255) / 256, 256, 0, stream>>>(x, xb,
                                                                      N_NODES * HID / 4);
    wt_kernel<<<6, 256, 0, stream>>>(W1, W2, Wt);

    const unsigned short* hcur = xb;
    for (int i = 0; i < N_LAYERS; ++i) {
        gather_kernel<<<(N_NODES + 15) / 16, 256, 0, stream>>>(hcur, cnt, csr, agg);
        mlp_kernel<<<(N_NODES + 63) / 64, 256, 0, stream>>>(
            agg, Wt + (size_t)(2 * i) * HID * HID, b1 + (size_t)i * HID,
            Wt + (size_t)(2 * i + 1) * HID * HID, b2 + (size_t)i * HID, hbuf);
        hcur = hbuf;
    }
    hipMemsetAsync(g, 0, (size_t)N_GRAPHS * HID * sizeof(float), stream);
    pool_kernel<<<(N_NODES + 255) / 256, 256, 0, stream>>>(hcur, batch, g);
    head_kernel<<<N_GRAPHS, 128, 0, stream>>>(g, Wmu, bmu, Wlv, blv, out);
}

// Round 11
// 466.386 us; speedup vs baseline: 1.7368x; 1.1500x over previous
//
#include <hip/hip_runtime.h>

#define N_NODES 100000
#define N_EDGES 1600000
#define HID 128
#define LAT 64
#define N_LAYERS 3
#define N_GRAPHS 1000
#define CAP 64                                    // slots per node (P(deg>=64)~1e-19)
#define NBIN 391                                  // dst bins of 256 nodes (d >> 8)
#define MAXBIN 4608                               // bin capacity: mean 4096 + 8*sigma
#define ACHUNK 8192
#define ABLOCKS ((N_EDGES + ACHUNK - 1) / ACHUNK) // 196

typedef short bf16x8 __attribute__((ext_vector_type(8)));
typedef float f32x4 __attribute__((ext_vector_type(4)));

__device__ __forceinline__ float bf2f(unsigned short h) {
    union { unsigned int u; float f; } c;
    c.u = ((unsigned int)h) << 16;
    return c.f;
}
__device__ __forceinline__ unsigned short f2bf(float f) {
    union { float f; unsigned int u; } c;
    c.f = f;
    unsigned int u = c.u;
    return (unsigned short)((u + 0x7fffu + ((u >> 16) & 1u)) >> 16);
}
__device__ __forceinline__ unsigned int pack2(float a, float b) {
    return (unsigned int)f2bf(a) | ((unsigned int)f2bf(b) << 16);
}
__device__ __forceinline__ void addrow(float* acc, uint4 w) {
    acc[0] += bf2f((unsigned short)w.x); acc[1] += bf2f((unsigned short)(w.x >> 16));
    acc[2] += bf2f((unsigned short)w.y); acc[3] += bf2f((unsigned short)(w.y >> 16));
    acc[4] += bf2f((unsigned short)w.z); acc[5] += bf2f((unsigned short)(w.z >> 16));
    acc[6] += bf2f((unsigned short)w.w); acc[7] += bf2f((unsigned short)(w.w >> 16));
}

// ---------------- convert x fp32 -> bf16 ----------------
__global__ __launch_bounds__(256) void cvt_x_kernel(const float* __restrict__ x,
                                                    unsigned short* __restrict__ xb, int n4) {
    int i = blockIdx.x * 256 + threadIdx.x;
    if (i >= n4) return;
    float4 v = ((const float4*)x)[i];
    ((uint2*)xb)[i] = make_uint2(pack2(v.x, v.y), pack2(v.z, v.w));
}

// ---------------- W [k][n] fp32 -> Wt [n][k] bf16, 6 matrices ----------------
__global__ __launch_bounds__(256) void wt_kernel(const float* __restrict__ W1,
                                                 const float* __restrict__ W2,
                                                 unsigned short* __restrict__ Wt) {
    int m = blockIdx.x;  // 0..5 : layer*2 + phase
    const float* W = ((m & 1) ? W2 : W1) + (size_t)(m >> 1) * HID * HID;
    unsigned short* D = Wt + (size_t)m * HID * HID;
    for (int idx = threadIdx.x; idx < HID * HID; idx += 256) {
        int n = idx >> 7, k = idx & 127;
        D[n * HID + k] = f2bf(W[k * HID + n]);
    }
}

// ---------------- binA: edges -> per-bin dense runs, packed (dlocal<<24)|src ----------------
// One block per 8192-edge chunk. LDS histogram over 391 bins, one global
// reservation per (block,bin), then dense run writes (no write amplification,
// 77k global atomics total instead of 1.6M).
__global__ __launch_bounds__(256) void binA_kernel(const int* __restrict__ ei,
                                                   int* __restrict__ gcnt,
                                                   unsigned int* __restrict__ ebin) {
    __shared__ unsigned int scount[NBIN];
    __shared__ unsigned int sfill[NBIN];
    int t = threadIdx.x;
    int base = blockIdx.x * ACHUNK;
    int n = N_EDGES - base;
    if (n > ACHUNK) n = ACHUNK;
    for (int i = t; i < NBIN; i += 256) scount[i] = 0u;
    __syncthreads();
    for (int i = t; i < n; i += 256) {
        int d = ei[N_EDGES + base + i];
        atomicAdd(&scount[d >> 8], 1u);
    }
    __syncthreads();
    for (int b = t; b < NBIN; b += 256) {
        unsigned int c = scount[b];
        sfill[b] = c ? (unsigned int)atomicAdd(&gcnt[b], (int)c) : 0u;
    }
    __syncthreads();
    for (int i = t; i < n; i += 256) {
        int s = ei[base + i];
        int d = ei[N_EDGES + base + i];
        int b = d >> 8;
        unsigned int pos = atomicAdd(&sfill[b], 1u);
        ebin[(size_t)b * MAXBIN + pos] = ((unsigned int)(d & 255) << 24) | (unsigned int)s;
    }
}

// ---------------- binB: drain bin -> slot csr, all block-local ----------------
// Block b owns nodes [b*256, b*256+256): csr window 64 KB + LDS cnt counters.
// Every atomic is an LDS atomic; every global write stays in one XCD's L2.
__global__ __launch_bounds__(256) void binB_kernel(const unsigned int* __restrict__ ebin,
                                                   const int* __restrict__ gcnt,
                                                   int* __restrict__ cnt,
                                                   int* __restrict__ csr) {
    __shared__ int scnt[256];
    int b = blockIdx.x;
    int t = threadIdx.x;
    scnt[t] = 0;
    __syncthreads();
    int n0 = b << 8;
    int c = gcnt[b];
    const unsigned int* src = ebin + (size_t)b * MAXBIN;
    for (int i = t; i < c; i += 256) {
        unsigned int e = src[i];
        int dl = (int)(e >> 24);
        int slot = atomicAdd(&scnt[dl], 1);
        csr[(size_t)(n0 + dl) * CAP + slot] = (int)(e & 0xFFFFFFu);
    }
    __syncthreads();
    int node = n0 + t;
    if (node < N_NODES) cnt[node] = scnt[t];
}

// ---------------- gather (bf16): agg[n] = h[n] + sum_{s in N(n)} h[s] ----------------
__global__ __launch_bounds__(256) void gather_kernel(const unsigned short* __restrict__ h,
                                                     const int* __restrict__ cnt,
                                                     const int* __restrict__ csr,
                                                     unsigned short* __restrict__ agg) {
    int t = threadIdx.x;
    int node = blockIdx.x * 16 + (t >> 4);
    int q = t & 15;
    if (node >= N_NODES) return;
    const int* nl = csr + (size_t)node * CAP;
    int deg = cnt[node];
    float acc[8] = {0.f, 0.f, 0.f, 0.f, 0.f, 0.f, 0.f, 0.f};
    addrow(acc, *(const uint4*)(h + (size_t)node * HID + q * 8));
    int e = 0;
    for (; e + 8 <= deg; e += 8) {
        int s0 = nl[e], s1 = nl[e + 1], s2 = nl[e + 2], s3 = nl[e + 3];
        int s4 = nl[e + 4], s5 = nl[e + 5], s6 = nl[e + 6], s7 = nl[e + 7];
        uint4 w0 = *(const uint4*)(h + (size_t)s0 * HID + q * 8);
        uint4 w1 = *(const uint4*)(h + (size_t)s1 * HID + q * 8);
        uint4 w2 = *(const uint4*)(h + (size_t)s2 * HID + q * 8);
        uint4 w3 = *(const uint4*)(h + (size_t)s3 * HID + q * 8);
        uint4 w4 = *(const uint4*)(h + (size_t)s4 * HID + q * 8);
        uint4 w5 = *(const uint4*)(h + (size_t)s5 * HID + q * 8);
        uint4 w6 = *(const uint4*)(h + (size_t)s6 * HID + q * 8);
        uint4 w7 = *(const uint4*)(h + (size_t)s7 * HID + q * 8);
        addrow(acc, w0); addrow(acc, w1); addrow(acc, w2); addrow(acc, w3);
        addrow(acc, w4); addrow(acc, w5); addrow(acc, w6); addrow(acc, w7);
    }
    for (; e + 4 <= deg; e += 4) {
        int s0 = nl[e], s1 = nl[e + 1], s2 = nl[e + 2], s3 = nl[e + 3];
        uint4 w0 = *(const uint4*)(h + (size_t)s0 * HID + q * 8);
        uint4 w1 = *(const uint4*)(h + (size_t)s1 * HID + q * 8);
        uint4 w2 = *(const uint4*)(h + (size_t)s2 * HID + q * 8);
        uint4 w3 = *(const uint4*)(h + (size_t)s3 * HID + q * 8);
        addrow(acc, w0); addrow(acc, w1); addrow(acc, w2); addrow(acc, w3);
    }
    for (; e < deg; ++e) {
        addrow(acc, *(const uint4*)(h + (size_t)nl[e] * HID + q * 8));
    }
    uint4 o;
    o.x = pack2(acc[0], acc[1]);
    o.y = pack2(acc[2], acc[3]);
    o.z = pack2(acc[4], acc[5]);
    o.w = pack2(acc[6], acc[7]);
    *(uint4*)(agg + (size_t)node * HID + q * 8) = o;
}

// ---------------- MFMA MLP (round-5 proven) ----------------
__global__ __launch_bounds__(256) void mlp_kernel(const unsigned short* __restrict__ A,
                                                  const unsigned short* __restrict__ W1t,
                                                  const float* __restrict__ b1,
                                                  const unsigned short* __restrict__ W2t,
                                                  const float* __restrict__ b2,
                                                  unsigned short* __restrict__ out) {
    __shared__ unsigned short sA[64][136];  // row stride 272B = 17*16B
    __shared__ unsigned short sW[128][40];  // row stride 80B = 5*16B
    __shared__ float sb[128];
    const int t = threadIdx.x;
    const int w = t >> 6;
    const int l = t & 63;
    const int lm = l & 15;
    const int quad = l >> 4;
    const int row0 = blockIdx.x * 64;

    for (int idx = t; idx < 1024; idx += 256) {
        int r = idx >> 4, c = idx & 15;
        int grow = row0 + r;
        uint4 v = make_uint4(0u, 0u, 0u, 0u);
        if (grow < N_NODES) v = *(const uint4*)(A + (size_t)grow * HID + c * 8);
        *(uint4*)&sA[r][c * 8] = v;
    }

    const unsigned short* Wt[2] = {W1t, W2t};
    const float* bias[2] = {b1, b2};

    for (int p = 0; p < 2; ++p) {
        if (t < 128) sb[t] = bias[p][t];
        f32x4 acc[8];
#pragma unroll
        for (int nt = 0; nt < 8; ++nt) acc[nt] = (f32x4){0.f, 0.f, 0.f, 0.f};

        for (int kc = 0; kc < 4; ++kc) {
            __syncthreads();
            for (int idx = t; idx < 512; idx += 256) {
                int n = idx >> 2, kq = idx & 3;
                *(uint4*)&sW[n][kq * 8] =
                    *(const uint4*)(Wt[p] + (size_t)n * HID + kc * 32 + kq * 8);
            }
            __syncthreads();
            bf16x8 a = *(const bf16x8*)&sA[w * 16 + lm][kc * 32 + quad * 8];
#pragma unroll
            for (int nt = 0; nt < 8; ++nt) {
                bf16x8 b = *(const bf16x8*)&sW[nt * 16 + lm][quad * 8];
                acc[nt] = __builtin_amdgcn_mfma_f32_16x16x32_bf16(a, b, acc[nt], 0, 0, 0);
            }
        }
        __syncthreads();
#pragma unroll
        for (int nt = 0; nt < 8; ++nt) {
            float bv = sb[nt * 16 + lm];
#pragma unroll
            for (int r = 0; r < 4; ++r) {
                int m = w * 16 + quad * 4 + r;
                float val = fmaxf(acc[nt][r] + bv, 0.f);
                sA[m][nt * 16 + lm] = f2bf(val);
            }
        }
        __syncthreads();
    }
    for (int idx = t; idx < 1024; idx += 256) {
        int r = idx >> 4, c = idx & 15;
        int grow = row0 + r;
        if (grow < N_NODES)
            *(uint4*)(out + (size_t)grow * HID + c * 8) = *(const uint4*)&sA[r][c * 8];
    }
}

// ---------------- pool (round-9 proven) ----------------
__global__ __launch_bounds__(256) void pool_kernel(const unsigned short* __restrict__ h,
                                                   const int* __restrict__ batch,
                                                   float* __restrict__ g) {
    const int S = 16;  // nodes per 16-lane group
    int t = threadIdx.x;
    int grp = t >> 4;
    int q = t & 15;
    int n0 = (blockIdx.x * 16 + grp) * S;
    if (n0 >= N_NODES) return;
    int n1 = n0 + S;
    if (n1 > N_NODES) n1 = N_NODES;
    int cur = batch[n0];
    float acc[8] = {0.f, 0.f, 0.f, 0.f, 0.f, 0.f, 0.f, 0.f};
    for (int n = n0; n < n1; ++n) {
        int b = batch[n];
        if (b != cur) {
            float* gp = g + (size_t)cur * HID + q * 8;
#pragma unroll
            for (int i = 0; i < 8; ++i) { atomicAdd(gp + i, acc[i]); acc[i] = 0.f; }
            cur = b;
        }
        addrow(acc, *(const uint4*)(h + (size_t)n * HID + q * 8));
    }
    float* gp = g + (size_t)cur * HID + q * 8;
#pragma unroll
    for (int i = 0; i < 8; ++i) atomicAdd(gp + i, acc[i]);
}

// ---------------- heads ----------------
__global__ __launch_bounds__(128) void head_kernel(const float* __restrict__ g,
                                                   const float* __restrict__ Wmu,
                                                   const float* __restrict__ bmu,
                                                   const float* __restrict__ Wlv,
                                                   const float* __restrict__ blv,
                                                   float* __restrict__ out) {
    __shared__ float sg[HID];
    int gi = blockIdx.x;
    sg[threadIdx.x] = g[(size_t)gi * HID + threadIdx.x];
    __syncthreads();
    int j = threadIdx.x & 63;
    bool is_lv = threadIdx.x >= 64;
    const float* W = is_lv ? Wlv : Wmu;
    float acc = is_lv ? blv[j] : bmu[j];
    for (int k = 0; k < HID; ++k) acc = fmaf(sg[k], W[k * LAT + j], acc);
    out[(is_lv ? (size_t)N_GRAPHS * LAT : 0) + (size_t)gi * LAT + j] = acc;
}

extern "C" void kernel_launch(void* const* d_in, const int* in_sizes, int n_in,
                              void* d_out, int out_size, void* d_ws, size_t ws_size,
                              hipStream_t stream) {
    const float* x     = (const float*)d_in[0];
    const int*   ei    = (const int*)d_in[1];
    const int*   batch = (const int*)d_in[2];
    const float* W1    = (const float*)d_in[3];
    const float* b1    = (const float*)d_in[4];
    const float* W2    = (const float*)d_in[5];
    const float* b2    = (const float*)d_in[6];
    const float* Wmu   = (const float*)d_in[7];
    const float* bmu   = (const float*)d_in[8];
    const float* Wlv   = (const float*)d_in[9];
    const float* blv   = (const float*)d_in[10];
    float* out = (float*)d_out;

    float* g = (float*)d_ws;                                       // 512 KB
    unsigned short* xb   = (unsigned short*)(g + (size_t)N_GRAPHS * HID);
    unsigned short* agg  = xb + (size_t)N_NODES * HID;             // 25.6 MB each
    unsigned short* hbuf = agg + (size_t)N_NODES * HID;
    unsigned short* Wt   = hbuf + (size_t)N_NODES * HID;           // 192 KB
    int* cnt  = (int*)(Wt + (size_t)6 * HID * HID);                // 400 KB
    int* gcnt = cnt + N_NODES;                                     // 1.6 KB
    int* csr  = gcnt + NBIN + 1;                                   // 25.6 MB
    unsigned int* ebin = (unsigned int*)(csr + (size_t)N_NODES * CAP);  // 7.2 MB

    // ---- CSR build: LDS-binned two-phase (no count/scan, no write amp) ----
    hipMemsetAsync(gcnt, 0, (size_t)NBIN * sizeof(int), stream);
    binA_kernel<<<ABLOCKS, 256, 0, stream>>>(ei, gcnt, ebin);
    binB_kernel<<<NBIN, 256, 0, stream>>>(ebin, gcnt, cnt, csr);

    // ---- prep bf16 ----
    cvt_x_kernel<<<(N_NODES * HID / 4 + 255) / 256, 256, 0, stream>>>(x, xb,
                                                                      N_NODES * HID / 4);
    wt_kernel<<<6, 256, 0, stream>>>(W1, W2, Wt);

    const unsigned short* hcur = xb;
    for (int i = 0; i < N_LAYERS; ++i) {
        gather_kernel<<<(N_NODES + 15) / 16, 256, 0, stream>>>(hcur, cnt, csr, agg);
        mlp_kernel<<<(N_NODES + 63) / 64, 256, 0, stream>>>(
            agg, Wt + (size_t)(2 * i) * HID * HID, b1 + (size_t)i * HID,
            Wt + (size_t)(2 * i + 1) * HID * HID, b2 + (size_t)i * HID, hbuf);
        hcur = hbuf;
    }
    hipMemsetAsync(g, 0, (size_t)N_GRAPHS * HID * sizeof(float), stream);
    pool_kernel<<<(N_NODES + 255) / 256, 256, 0, stream>>>(hcur, batch, g);
    head_kernel<<<N_GRAPHS, 128, 0, stream>>>(g, Wmu, bmu, Wlv, blv, out);
}